// Round 17
// baseline (69.921 us; speedup 1.0000x reference)
//
#include <hip/hip_runtime.h>
#include <hip/hip_bf16.h>
#include <stdint.h>

#define G1CAST(p) ((const __attribute__((address_space(1))) void*)(p))
#define L3CAST(p) ((__attribute__((address_space(3))) void*)(p))

typedef short bf16x8 __attribute__((ext_vector_type(8)));
typedef float f32x16 __attribute__((ext_vector_type(16)));

static __device__ __forceinline__ short f2bf(float f) {
    __hip_bfloat16 b = __float2bfloat16(f);
    return __builtin_bit_cast(short, b);
}

// ---------------------------------------------------------------------------
// Kernel 1: weights -> bf16, step-block layout (R13-proven, unchanged).
// Wstep[(nblk*8+jt)*64+s] is a contiguous 6144B block:
//   [wn 0..1][g 0..2][lane 0..63][16B]
//   j = jt*64 + wn*32 + (lane&31),  kk = s*16 + (lane>>5)*8 + t, t=0..7
// ---------------------------------------------------------------------------
__global__ __launch_bounds__(256) void wconv_kernel(const float* __restrict__ Wih,
                                                    const float* __restrict__ Whh,
                                                    short* __restrict__ Wstep) {
    const int b = blockIdx.x;                         // 6144
    const int vb = (b & 7) * 768 + (b >> 3);          // XCD-aligned permute
    const int gid = vb * 256 + threadIdx.x;
    const int lane = gid & 63;
    int t1 = gid >> 6;
    const int g = t1 % 3;  t1 /= 3;
    const int wn = t1 & 1; t1 >>= 1;
    const int s = t1 & 63; t1 >>= 6;
    const int jt = t1 & 7;
    const int nblk = t1 >> 3;
    const int j = jt * 64 + wn * 32 + (lane & 31);
    const int kk = s * 16 + (lane >> 5) * 8;
    const float* src = (kk < 512)
        ? Wih + ((int64_t)nblk * 786432 + (int64_t)(g * 512 + j) * 512 + kk)
        : Whh + ((int64_t)nblk * 786432 + (int64_t)(g * 512 + j) * 512 + (kk - 512));
    const float4 a = ((const float4*)src)[0];
    const float4 bq = ((const float4*)src)[1];
    bf16x8 o;
    o[0] = f2bf(a.x); o[1] = f2bf(a.y); o[2] = f2bf(a.z); o[3] = f2bf(a.w);
    o[4] = f2bf(bq.x); o[5] = f2bf(bq.y); o[6] = f2bf(bq.z); o[7] = f2bf(bq.w);
    *(bf16x8*)(Wstep + (size_t)gid * 8) = o;
}

// ---------------------------------------------------------------------------
// Kernel 1b: x,h -> bf16 A-image in MFMA fragment order (R13-proven).
// Afrag[rb 0..31][nblk 0..7][s 0..63][lane 0..63][8 bf16]:
//   row = rb*32 + (lane&31),  kk = s*16 + (lane>>5)*8  (kk<512 = x, else h)
// ---------------------------------------------------------------------------
__global__ __launch_bounds__(256) void aconv_kernel(const float* __restrict__ x,
                                                    const float* __restrict__ h,
                                                    short* __restrict__ Afrag) {
    const int b = blockIdx.x;                 // 4096
    const int n = b & 7;                      // == consumer XCD
    const int inner = b >> 3;                 // 0..511
    const int rb = inner >> 4;                // 0..31
    const int u = inner & 15;                 // 0..15
    const int tid = threadIdx.x;
    const int lane = tid & 63;
    const int s = u * 4 + (tid >> 6);         // 0..63
    const int row = rb * 32 + (lane & 31);
    const int kk = s * 16 + (lane >> 5) * 8;  // 0..1023
    const float* src = (kk < 512)
        ? x + ((size_t)row * 4096 + n * 512 + kk)
        : h + ((size_t)row * 4096 + n * 512 + (kk - 512));
    const float4 a = ((const float4*)src)[0];
    const float4 bq = ((const float4*)src)[1];
    bf16x8 o;
    o[0] = f2bf(a.x); o[1] = f2bf(a.y); o[2] = f2bf(a.z); o[3] = f2bf(a.w);
    o[4] = f2bf(bq.x); o[5] = f2bf(bq.y); o[6] = f2bf(bq.z); o[7] = f2bf(bq.w);
    const size_t dst = ((((size_t)(rb * 8 + n) * 64 + s) * 64) + lane) * 8;
    *(bf16x8*)(Afrag + dst) = o;
}

// ---------------------------------------------------------------------------
// Kernel 2: fused block-diagonal GRU — DECOUPLED PIPELINE.
// BM=64 x BN=64(x3 gates), 256 thr = 4 waves (2wm x 2wn), wave tile 32x32,
// acc = 4 x f32x16 = 64 AGPR. Grid 1024. LDS = ring-6 x 8192B = 48 KB.
//
// Key change vs R13/R15: ds_read at iter s fetches fragments for step s+2
// into a 4-deep named register rotation, so MFMA(s) uses registers loaded
// 2 iterations ago — NO same-iteration LDS round trip on the MFMA path.
//
// FIFO audit (per wave, 3 VMEM ops/iter in order [Bstage,Bstage,Aload]):
//   iter s issues stage B(s+5) -> slot (s+5)%6 and load A(s+3).
//   vmcnt(4) at top of iter s leaves s-1's triple + s-2's A outstanding =>
//   own B-stages through step s+3 and A(s) retired. Every wave executes
//   vmcnt(4) before s_barrier(s), so after the barrier all waves' B-writes
//   for slots <= s+2 are visible => ds_read(s+2) at iter s is safe.
//   Slot rewrite (s+5)%6 == slot of step s-1: its reads happened at iter
//   s-3, lgkm-retired before MFMA(s-1), sequenced before barrier(s). Safe.
// ---------------------------------------------------------------------------
__global__ __launch_bounds__(256, 3) void gru_kernel(
    const float* __restrict__ hst,
    const short* __restrict__ Wstep, const short* __restrict__ Afrag,
    const float* __restrict__ b_ih, const float* __restrict__ b_hh,
    float* __restrict__ out)
{
    __shared__ __align__(16) char ldsB[6][8192];   // 48 KB ring

    const int tid = threadIdx.x;
    const int nblk = blockIdx.x & 7;          // XCD-local weight slice
    const int rr_ = blockIdx.x >> 3;          // 0..127
    const int jt = rr_ & 7;                   // j tile (fast -> L2 reuse)
    const int bt = rr_ >> 3;                  // 0..15 batch tile (slow)
    const int brow0 = bt * 64;

    const int lane = tid & 63;
    const int wave = tid >> 6;                // 0..3
    const int wm = wave >> 1;                 // 0..1 (32-row slice)
    const int wn = wave & 1;                  // 0..1 (32-col slice)
    const int l31 = lane & 31;
    const int k8 = lane >> 5;

    // B staging (R13-proven pad scheme): wave w stages [w*2048, +2048)
    const int d0 = wave * 2048;
    const int ssrc0 = (d0 >= 6144) ? d0 - 6144 : d0;
    const int ssrc1 = (d0 + 1024 >= 6144) ? d0 + 1024 - 6144 : d0 + 1024;
    const char* wstep0 = (const char*)Wstep + (size_t)((nblk * 8 + jt) * 64) * 6144
                       + (size_t)lane * 16;
    // A fragment stream: rb = bt*2 + wm
    const char* ab = (const char*)Afrag
        + ((size_t)((bt * 2 + wm) * 8 + nblk) << 16) + (size_t)lane * 16;
    const int boff = (wn * 3) * 1024 + lane * 16;
    const char* ldsBase = &ldsB[0][0];

    f32x16 acc_r = {};
    f32x16 acc_z = {};
    f32x16 acc_nx = {};
    f32x16 acc_nh = {};

    bf16x8 a_0, a_1, a_2, a_3;                               // A rotation (depth 3)
    bf16x8 b0_0, b1_0, b2_0, b0_1, b1_1, b2_1;               // B frag sets
    bf16x8 b0_2, b1_2, b2_2, b0_3, b1_3, b2_3;               // (depth 2, period 4)

#define LDA(T, s_v)                                                        \
    {                                                                      \
        const int sc = (s_v) > 63 ? 63 : (s_v);                            \
        a_##T = *(const bf16x8*)(ab + (size_t)sc * 1024);                  \
    }

    auto stageB = [&](int s, int off) {
        const int sc = s > 63 ? 63 : s;
        const char* src = wstep0 + (size_t)sc * 6144;
        char* dst = (char*)ldsBase + off + d0;
        __builtin_amdgcn_global_load_lds(G1CAST(src + ssrc0), L3CAST(dst), 16, 0, 0);
        __builtin_amdgcn_global_load_lds(G1CAST(src + ssrc1), L3CAST(dst + 1024), 16, 0, 0);
    };

// iter s: AC = A set used (s%4), AL = A set loaded ((s+3)%4),
//         BU = B set used (s%4), BR = B set read ((s+2)%4)
#define ITER(AC, AL, BU, BR, accN)                                                  \
    {                                                                               \
        asm volatile("s_waitcnt vmcnt(4)" ::: "memory");                            \
        __builtin_amdgcn_s_barrier();                                               \
        const char* rp = ldsBase + rdoff + boff;                                    \
        b0_##BR = *(const bf16x8*)(rp);                                             \
        b1_##BR = *(const bf16x8*)(rp + 1024);                                      \
        b2_##BR = *(const bf16x8*)(rp + 2048);                                      \
        stageB(s_ + 5, stoff);                                                      \
        LDA(AL, s_ + 3)                                                             \
        __builtin_amdgcn_s_setprio(1);                                              \
        acc_r = __builtin_amdgcn_mfma_f32_32x32x16_bf16(a_##AC, b0_##BU, acc_r, 0, 0, 0); \
        acc_z = __builtin_amdgcn_mfma_f32_32x32x16_bf16(a_##AC, b1_##BU, acc_z, 0, 0, 0); \
        accN  = __builtin_amdgcn_mfma_f32_32x32x16_bf16(a_##AC, b2_##BU, accN, 0, 0, 0);  \
        __builtin_amdgcn_s_setprio(0);                                              \
        rdoff += 8192; if (rdoff >= 49152) rdoff -= 49152;                          \
        stoff += 8192; if (stoff >= 49152) stoff -= 49152;                          \
        s_ += 1;                                                                    \
    }

#define GROUP(accN)          \
    ITER(0, 3, 0, 2, accN)   \
    ITER(1, 0, 1, 3, accN)   \
    ITER(2, 1, 2, 0, accN)   \
    ITER(3, 2, 3, 1, accN)

    // ---- prologue ----
    // VMEM order: A(0),A(1),A(2), B(0)x2..B(4)x2  (13 ops)
    LDA(0, 0) LDA(1, 1) LDA(2, 2)
    stageB(0, 0); stageB(1, 8192); stageB(2, 16384);
    stageB(3, 24576); stageB(4, 32768);
    // vmcnt(4): retires A(0..2), B(0..2) (newest 4 = B3b,B4a,B4b,B3a..)
    asm volatile("s_waitcnt vmcnt(4)" ::: "memory");
    __builtin_amdgcn_s_barrier();                 // publish slots 0..2
    {   // pre-read fragment sets 0 and 1 (steps 0,1)
        const char* rp0 = ldsBase + boff;
        b0_0 = *(const bf16x8*)(rp0);
        b1_0 = *(const bf16x8*)(rp0 + 1024);
        b2_0 = *(const bf16x8*)(rp0 + 2048);
        const char* rp1 = ldsBase + 8192 + boff;
        b0_1 = *(const bf16x8*)(rp1);
        b1_1 = *(const bf16x8*)(rp1 + 1024);
        b2_1 = *(const bf16x8*)(rp1 + 2048);
    }

    int s_ = 0;
    int rdoff = 16384;                        // slot (s+2)%6 = 2
    int stoff = 40960;                        // slot (s+5)%6 = 5

    #pragma unroll 1
    for (int g8 = 0; g8 < 8; ++g8) {          // steps 0..31 -> acc_nx
        GROUP(acc_nx)
    }
    #pragma unroll 1
    for (int g8 = 0; g8 < 8; ++g8) {          // steps 32..63 -> acc_nh
        GROUP(acc_nh)
    }
#undef GROUP
#undef ITER
#undef LDA

    // ---- epilogue: gates + output (wave owns 32x32 tile) ----
    const int jb = jt * 64 + wn * 32 + l31;   // [0,512)
    const int bb = nblk * 1536 + jb;
    const float br = b_ih[bb] + b_hh[bb];
    const float bz = b_ih[bb + 512] + b_hh[bb + 512];
    const float bnx = b_ih[bb + 1024];
    const float bnh = b_hh[bb + 1024];
    const int gcol = nblk * 512 + jb;
    #pragma unroll
    for (int rr = 0; rr < 16; ++rr) {
        const int rowl = (rr & 3) + 8 * (rr >> 2) + 4 * k8;
        const int row = brow0 + wm * 32 + rowl;
        const size_t idx = (size_t)row * 4096 + gcol;
        const float sr = acc_r[rr] + br;
        const float sz = acc_z[rr] + bz;
        const float rg = 1.f / (1.f + __expf(-sr));
        const float zg = 1.f / (1.f + __expf(-sz));
        const float tin = (acc_nx[rr] + bnx) + rg * (acc_nh[rr] + bnh);
        const float e2 = __expf(-2.f * tin);
        const float ng = 2.f / (1.f + e2) - 1.f;
        const float hv = hst[idx];
        out[idx] = ng + zg * (hv - ng);
    }
}

extern "C" void kernel_launch(void* const* d_in, const int* in_sizes, int n_in,
                              void* d_out, int out_size, void* d_ws, size_t ws_size,
                              hipStream_t stream) {
    (void)in_sizes; (void)n_in; (void)out_size; (void)ws_size;
    const float* x    = (const float*)d_in[0];
    const float* h    = (const float*)d_in[1];
    const float* W_ih = (const float*)d_in[2];
    const float* W_hh = (const float*)d_in[3];
    const float* b_ih = (const float*)d_in[4];
    const float* b_hh = (const float*)d_in[5];
    short* Wstep = (short*)d_ws;                              // 24 MB
    short* Afrag = (short*)d_ws + (size_t)12 * 1024 * 1024;   // 16 MB

    wconv_kernel<<<6144, 256, 0, stream>>>(W_ih, W_hh, Wstep);
    aconv_kernel<<<4096, 256, 0, stream>>>(x, h, Afrag);
    gru_kernel<<<1024, 256, 0, stream>>>(h, Wstep, Afrag, b_ih, b_hh, (float*)d_out);
}

// Round 18
// 63.764 us; speedup vs baseline: 1.0966x; 1.0966x over previous
//
#include <hip/hip_runtime.h>
#include <hip/hip_bf16.h>
#include <stdint.h>

#define G1CAST(p) ((const __attribute__((address_space(1))) void*)(p))
#define L3CAST(p) ((__attribute__((address_space(3))) void*)(p))

typedef short bf16x8 __attribute__((ext_vector_type(8)));
typedef float f32x16 __attribute__((ext_vector_type(16)));

static __device__ __forceinline__ short f2bf(float f) {
    __hip_bfloat16 b = __float2bfloat16(f);
    return __builtin_bit_cast(short, b);
}

// ---------------------------------------------------------------------------
// Kernel 1: weights -> bf16, step-block layout (R13-proven, unchanged).
// Wstep[(nblk*8+jt)*64+s] is a contiguous 6144B block:
//   [wn 0..1][g 0..2][lane 0..63][16B]
//   j = jt*64 + wn*32 + (lane&31),  kk = s*16 + (lane>>5)*8 + t, t=0..7
// ---------------------------------------------------------------------------
__global__ __launch_bounds__(256) void wconv_kernel(const float* __restrict__ Wih,
                                                    const float* __restrict__ Whh,
                                                    short* __restrict__ Wstep) {
    const int b = blockIdx.x;                         // 6144
    const int vb = (b & 7) * 768 + (b >> 3);          // XCD-aligned permute
    const int gid = vb * 256 + threadIdx.x;
    const int lane = gid & 63;
    int t1 = gid >> 6;
    const int g = t1 % 3;  t1 /= 3;
    const int wn = t1 & 1; t1 >>= 1;
    const int s = t1 & 63; t1 >>= 6;
    const int jt = t1 & 7;
    const int nblk = t1 >> 3;
    const int j = jt * 64 + wn * 32 + (lane & 31);
    const int kk = s * 16 + (lane >> 5) * 8;
    const float* src = (kk < 512)
        ? Wih + ((int64_t)nblk * 786432 + (int64_t)(g * 512 + j) * 512 + kk)
        : Whh + ((int64_t)nblk * 786432 + (int64_t)(g * 512 + j) * 512 + (kk - 512));
    const float4 a = ((const float4*)src)[0];
    const float4 bq = ((const float4*)src)[1];
    bf16x8 o;
    o[0] = f2bf(a.x); o[1] = f2bf(a.y); o[2] = f2bf(a.z); o[3] = f2bf(a.w);
    o[4] = f2bf(bq.x); o[5] = f2bf(bq.y); o[6] = f2bf(bq.z); o[7] = f2bf(bq.w);
    *(bf16x8*)(Wstep + (size_t)gid * 8) = o;
}

// ---------------------------------------------------------------------------
// Kernel 1b: x,h -> bf16 A-image in MFMA fragment order (R13-proven).
// Afrag[rb 0..31][nblk 0..7][s 0..63][lane 0..63][8 bf16]:
//   row = rb*32 + (lane&31),  kk = s*16 + (lane>>5)*8  (kk<512 = x, else h)
// ---------------------------------------------------------------------------
__global__ __launch_bounds__(256) void aconv_kernel(const float* __restrict__ x,
                                                    const float* __restrict__ h,
                                                    short* __restrict__ Afrag) {
    const int b = blockIdx.x;                 // 4096
    const int n = b & 7;                      // == consumer XCD
    const int inner = b >> 3;                 // 0..511
    const int rb = inner >> 4;                // 0..31
    const int u = inner & 15;                 // 0..15
    const int tid = threadIdx.x;
    const int lane = tid & 63;
    const int s = u * 4 + (tid >> 6);         // 0..63
    const int row = rb * 32 + (lane & 31);
    const int kk = s * 16 + (lane >> 5) * 8;  // 0..1023
    const float* src = (kk < 512)
        ? x + ((size_t)row * 4096 + n * 512 + kk)
        : h + ((size_t)row * 4096 + n * 512 + (kk - 512));
    const float4 a = ((const float4*)src)[0];
    const float4 bq = ((const float4*)src)[1];
    bf16x8 o;
    o[0] = f2bf(a.x); o[1] = f2bf(a.y); o[2] = f2bf(a.z); o[3] = f2bf(a.w);
    o[4] = f2bf(bq.x); o[5] = f2bf(bq.y); o[6] = f2bf(bq.z); o[7] = f2bf(bq.w);
    const size_t dst = ((((size_t)(rb * 8 + n) * 64 + s) * 64) + lane) * 8;
    *(bf16x8*)(Afrag + dst) = o;
}

// ---------------------------------------------------------------------------
// Kernel 2: fused block-diagonal GRU — BK=64/iter (4 substeps), 16 iters.
// BM=64 x BN=64(x3 gates), 256 thr = 4 waves (2wm x 2wn), wave tile 32x32,
// acc = 4 x f32x16 = 64 regs. Grid 1024. LDS = ring-3 x 24576B = 72 KB
// -> 2 blocks/CU. Per iteration: 12 MFMAs/wave (384 cyc payload) against
// ONE barrier + ONE vmcnt — amortizes the ~1200cyc fixed cost 4x vs R13.
//
// Staging: wave w stages substep w of the 24KB slot = 6144B = 6 x 16B
// gload_lds (uniform, no pad). A: register prefetch, 2 named quads.
// VMEM/wave/iter = 10 (6 B + 4 A).
// FIFO audit: vmcnt(10) at iter i leaves iter i-1's 10 ops outstanding =>
// stage(i) (issued iter i-2) retired before barrier(i) => slot i%3 readable.
// Slot overwrite (i+2)%3=(i-1)%3: its iter-(i-1) ds_reads lgkm-retired
// before that iter's MFMAs, hence before barrier(i). Tail: clamped dummy
// stages keep counts uniform; dummy slots never read again.
// ---------------------------------------------------------------------------
__global__ __launch_bounds__(256, 2) void gru_kernel(
    const float* __restrict__ hst,
    const short* __restrict__ Wstep, const short* __restrict__ Afrag,
    const float* __restrict__ b_ih, const float* __restrict__ b_hh,
    float* __restrict__ out)
{
    __shared__ __align__(16) char ldsB[3][24576];   // 72 KB ring

    const int tid = threadIdx.x;
    const int nblk = blockIdx.x & 7;          // XCD-local weight slice
    const int rr_ = blockIdx.x >> 3;          // 0..127
    const int jt = rr_ & 7;                   // j tile (fast -> L2 reuse)
    const int bt = rr_ >> 3;                  // 0..15 batch tile (slow)
    const int brow0 = bt * 64;

    const int lane = tid & 63;
    const int wave = tid >> 6;                // 0..3
    const int wm = wave >> 1;                 // 0..1 (32-row slice)
    const int wn = wave & 1;                  // 0..1 (32-col slice)
    const int l31 = lane & 31;
    const int k8 = lane >> 5;

    // B staging: wave w stages substep w (6144B) of each iter's 24KB slot
    const char* wstep0 = (const char*)Wstep + (size_t)((nblk * 8 + jt) * 64) * 6144
                       + (size_t)wave * 6144 + (size_t)lane * 16;
    const int bdst0 = wave * 6144 + lane * 16;
    // A fragment stream: rb = bt*2 + wm
    const char* ab = (const char*)Afrag
        + ((size_t)((bt * 2 + wm) * 8 + nblk) << 16) + (size_t)lane * 16;
    // B read offset within a substep
    const int boff = (wn * 3) * 1024 + lane * 16;

    f32x16 acc_r = {};
    f32x16 acc_z = {};
    f32x16 acc_nx = {};
    f32x16 acc_nh = {};

    bf16x8 aC0, aC1, aC2, aC3, aN0, aN1, aN2, aN3;   // 2 named A quads

#define LDA4(T, it)                                                        \
    {                                                                      \
        const int ic = (it) > 15 ? 15 : (it);                              \
        const char* ap = ab + (size_t)(ic * 4) * 1024;                     \
        a##T##0 = *(const bf16x8*)(ap);                                    \
        a##T##1 = *(const bf16x8*)(ap + 1024);                             \
        a##T##2 = *(const bf16x8*)(ap + 2048);                             \
        a##T##3 = *(const bf16x8*)(ap + 3072);                             \
    }

    auto stageB = [&](int it, int slot) {
        const int ic = it > 15 ? 15 : it;
        const char* src = wstep0 + (size_t)(ic * 4) * 6144;   // substep wave of iter ic
        char* dst = (char*)&ldsB[slot][0] + bdst0;
        #pragma unroll
        for (int c = 0; c < 6; ++c)
            __builtin_amdgcn_global_load_lds(G1CAST(src + c * 1024),
                                             L3CAST(dst + c * 1024), 16, 0, 0);
    };

#define SUBSTEP(T, u, accN)                                                         \
    {                                                                               \
        const char* bp = (const char*)&ldsB[0][0] + rdoff + (u) * 6144 + boff;      \
        bf16x8 b0 = *(const bf16x8*)(bp);                                           \
        bf16x8 b1 = *(const bf16x8*)(bp + 1024);                                    \
        bf16x8 b2 = *(const bf16x8*)(bp + 2048);                                    \
        acc_r = __builtin_amdgcn_mfma_f32_32x32x16_bf16(a##T##u, b0, acc_r, 0, 0, 0); \
        acc_z = __builtin_amdgcn_mfma_f32_32x32x16_bf16(a##T##u, b1, acc_z, 0, 0, 0); \
        accN  = __builtin_amdgcn_mfma_f32_32x32x16_bf16(a##T##u, b2, accN, 0, 0, 0);  \
    }

#define ITER(T, O, accN)                                                            \
    {                                                                               \
        asm volatile("s_waitcnt vmcnt(10)" ::: "memory");                           \
        __builtin_amdgcn_s_barrier();                                               \
        stageB(i_ + 2, stslot);                                                     \
        LDA4(O, i_ + 1)                                                             \
        SUBSTEP(T, 0, accN)                                                         \
        SUBSTEP(T, 1, accN)                                                         \
        SUBSTEP(T, 2, accN)                                                         \
        SUBSTEP(T, 3, accN)                                                         \
        rdoff += 24576; if (rdoff >= 73728) rdoff -= 73728;                         \
        stslot = (stslot == 2) ? 0 : stslot + 1;                                    \
        i_ += 1;                                                                    \
    }

    // prologue: stage iters 0,1 into slots 0,1 (12 ops) + A(0) (4 ops)
    stageB(0, 0); stageB(1, 1);
    LDA4(C, 0)

    int i_ = 0;
    int rdoff = 0;                            // byte offset of slot i%3
    int stslot = 2;                           // slot (i+2)%3

    #pragma unroll 1
    for (int g2 = 0; g2 < 4; ++g2) {          // iters 0..7: steps 0..31 -> acc_nx
        ITER(C, N, acc_nx)
        ITER(N, C, acc_nx)
    }
    #pragma unroll 1
    for (int g2 = 0; g2 < 4; ++g2) {          // iters 8..15: steps 32..63 -> acc_nh
        ITER(C, N, acc_nh)
        ITER(N, C, acc_nh)
    }
#undef ITER
#undef SUBSTEP
#undef LDA4

    // ---- epilogue: gates + output (wave owns 32x32 tile) ----
    const int jb = jt * 64 + wn * 32 + l31;   // [0,512)
    const int bb = nblk * 1536 + jb;
    const float br = b_ih[bb] + b_hh[bb];
    const float bz = b_ih[bb + 512] + b_hh[bb + 512];
    const float bnx = b_ih[bb + 1024];
    const float bnh = b_hh[bb + 1024];
    const int gcol = nblk * 512 + jb;
    #pragma unroll
    for (int rr = 0; rr < 16; ++rr) {
        const int rowl = (rr & 3) + 8 * (rr >> 2) + 4 * k8;
        const int row = brow0 + wm * 32 + rowl;
        const size_t idx = (size_t)row * 4096 + gcol;
        const float sr = acc_r[rr] + br;
        const float sz = acc_z[rr] + bz;
        const float rg = 1.f / (1.f + __expf(-sr));
        const float zg = 1.f / (1.f + __expf(-sz));
        const float tin = (acc_nx[rr] + bnx) + rg * (acc_nh[rr] + bnh);
        const float e2 = __expf(-2.f * tin);
        const float ng = 2.f / (1.f + e2) - 1.f;
        const float hv = hst[idx];
        out[idx] = ng + zg * (hv - ng);
    }
}

extern "C" void kernel_launch(void* const* d_in, const int* in_sizes, int n_in,
                              void* d_out, int out_size, void* d_ws, size_t ws_size,
                              hipStream_t stream) {
    (void)in_sizes; (void)n_in; (void)out_size; (void)ws_size;
    const float* x    = (const float*)d_in[0];
    const float* h    = (const float*)d_in[1];
    const float* W_ih = (const float*)d_in[2];
    const float* W_hh = (const float*)d_in[3];
    const float* b_ih = (const float*)d_in[4];
    const float* b_hh = (const float*)d_in[5];
    short* Wstep = (short*)d_ws;                              // 24 MB
    short* Afrag = (short*)d_ws + (size_t)12 * 1024 * 1024;   // 16 MB

    wconv_kernel<<<6144, 256, 0, stream>>>(W_ih, W_hh, Wstep);
    aconv_kernel<<<4096, 256, 0, stream>>>(x, h, Afrag);
    gru_kernel<<<1024, 256, 0, stream>>>(h, Wstep, Afrag, b_ih, b_hh, (float*)d_out);
}

// Round 19
// 62.675 us; speedup vs baseline: 1.1156x; 1.0174x over previous
//
#include <hip/hip_runtime.h>
#include <hip/hip_bf16.h>
#include <stdint.h>

#define G1CAST(p) ((const __attribute__((address_space(1))) void*)(p))
#define L3CAST(p) ((__attribute__((address_space(3))) void*)(p))

typedef short bf16x8 __attribute__((ext_vector_type(8)));
typedef float f32x16 __attribute__((ext_vector_type(16)));

static __device__ __forceinline__ short f2bf(float f) {
    __hip_bfloat16 b = __float2bfloat16(f);
    return __builtin_bit_cast(short, b);
}

// ---------------------------------------------------------------------------
// Kernel 1: weights -> bf16, step-block layout (R13-proven, unchanged).
// Wstep[(nblk*8+jt)*64+s] is a contiguous 6144B block:
//   [wn 0..1][g 0..2][lane 0..63][16B]
//   j = jt*64 + wn*32 + (lane&31),  kk = s*16 + (lane>>5)*8 + t, t=0..7
// ---------------------------------------------------------------------------
__global__ __launch_bounds__(256) void wconv_kernel(const float* __restrict__ Wih,
                                                    const float* __restrict__ Whh,
                                                    short* __restrict__ Wstep) {
    const int b = blockIdx.x;                         // 6144
    const int vb = (b & 7) * 768 + (b >> 3);          // XCD-aligned permute
    const int gid = vb * 256 + threadIdx.x;
    const int lane = gid & 63;
    int t1 = gid >> 6;
    const int g = t1 % 3;  t1 /= 3;
    const int wn = t1 & 1; t1 >>= 1;
    const int s = t1 & 63; t1 >>= 6;
    const int jt = t1 & 7;
    const int nblk = t1 >> 3;
    const int j = jt * 64 + wn * 32 + (lane & 31);
    const int kk = s * 16 + (lane >> 5) * 8;
    const float* src = (kk < 512)
        ? Wih + ((int64_t)nblk * 786432 + (int64_t)(g * 512 + j) * 512 + kk)
        : Whh + ((int64_t)nblk * 786432 + (int64_t)(g * 512 + j) * 512 + (kk - 512));
    const float4 a = ((const float4*)src)[0];
    const float4 bq = ((const float4*)src)[1];
    bf16x8 o;
    o[0] = f2bf(a.x); o[1] = f2bf(a.y); o[2] = f2bf(a.z); o[3] = f2bf(a.w);
    o[4] = f2bf(bq.x); o[5] = f2bf(bq.y); o[6] = f2bf(bq.z); o[7] = f2bf(bq.w);
    *(bf16x8*)(Wstep + (size_t)gid * 8) = o;
}

// ---------------------------------------------------------------------------
// Kernel 1b: x,h -> bf16 A-image in MFMA fragment order (R13-proven).
// Afrag[rb 0..31][nblk 0..7][s 0..63][lane 0..63][8 bf16]:
//   row = rb*32 + (lane&31),  kk = s*16 + (lane>>5)*8  (kk<512 = x, else h)
// ---------------------------------------------------------------------------
__global__ __launch_bounds__(256) void aconv_kernel(const float* __restrict__ x,
                                                    const float* __restrict__ h,
                                                    short* __restrict__ Afrag) {
    const int b = blockIdx.x;                 // 4096
    const int n = b & 7;                      // == consumer XCD
    const int inner = b >> 3;                 // 0..511
    const int rb = inner >> 4;                // 0..31
    const int u = inner & 15;                 // 0..15
    const int tid = threadIdx.x;
    const int lane = tid & 63;
    const int s = u * 4 + (tid >> 6);         // 0..63
    const int row = rb * 32 + (lane & 31);
    const int kk = s * 16 + (lane >> 5) * 8;  // 0..1023
    const float* src = (kk < 512)
        ? x + ((size_t)row * 4096 + n * 512 + kk)
        : h + ((size_t)row * 4096 + n * 512 + (kk - 512));
    const float4 a = ((const float4*)src)[0];
    const float4 bq = ((const float4*)src)[1];
    bf16x8 o;
    o[0] = f2bf(a.x); o[1] = f2bf(a.y); o[2] = f2bf(a.z); o[3] = f2bf(a.w);
    o[4] = f2bf(bq.x); o[5] = f2bf(bq.y); o[6] = f2bf(bq.z); o[7] = f2bf(bq.w);
    const size_t dst = ((((size_t)(rb * 8 + n) * 64 + s) * 64) + lane) * 8;
    *(bf16x8*)(Afrag + dst) = o;
}

// ---------------------------------------------------------------------------
// Kernel 2: fused block-diagonal GRU — CACHE-TRAFFIC-MINIMIZED.
// BM=256 x BN=64(x3 gates), 512 thr = 8 waves (4wm x 2wn), wave tile 64x32
// (m_rep=2), acc = 8 x f32x16 = 128 regs. Grid 256 = 1 block/CU.
// Theory: all prior variants saturate ~11-16 TB/s of L2/L3-side traffic
// (R11 655MB/40us, R17 655MB/46us, R13 459MB/42us). This tile + LDS-dedup
// of BOTH operands cuts chip traffic to 229 MB.
// LDS 136KB: B ring-3 x 24KB (BK=64 slot) + A dbuf-2 x 32KB.
// Uniform 7 VMEM/thread/iter, issued [A(i+1) x4, B(i+2) x3].
// FIFO: top-of-iter outstanding = [B(i)x3, A(i)x4, B(i+1)x3] -> vmcnt(3)
// retires B(i)+A(i), leaves B(i+1) in flight (never drains cold).
// Slot audits: B slot (i+2)%3 last read at i-1 (reads lgkm-retired before
// barrier(i)); A slot (i+1)&1 last read at i-1. Tails clamped (dummy
// restages land in slots never read again).
// ---------------------------------------------------------------------------
__global__ __launch_bounds__(512, 1) void gru_kernel(
    const float* __restrict__ hst,
    const short* __restrict__ Wstep, const short* __restrict__ Afrag,
    const float* __restrict__ b_ih, const float* __restrict__ b_hh,
    float* __restrict__ out)
{
    __shared__ __align__(16) char ldsB[3][24576];   // 72 KB
    __shared__ __align__(16) char ldsA[2][32768];   // 64 KB

    const int tid = threadIdx.x;
    const int nblk = blockIdx.x & 7;          // XCD pin
    const int jt = (blockIdx.x >> 3) & 7;     // j tile
    const int bt = blockIdx.x >> 6;           // 0..3 batch tile
    const int brow0 = bt * 256;

    const int lane = tid & 63;
    const int wave = tid >> 6;                // 0..7
    const int wm = wave >> 1;                 // 0..3 (64-row slice)
    const int wn = wave & 1;                  // 0..1 (32-col slice)
    const int l31 = lane & 31;
    const int k8 = lane >> 5;

    // ---- B staging: wave w stages [w*3072, +3072) of the 24KB iter-slot ----
    const char* bsrc0 = (const char*)Wstep + (size_t)((nblk * 8 + jt) * 64) * 6144
                      + (size_t)wave * 3072 + (size_t)lane * 16;
    const int bdst0 = wave * 3072 + lane * 16;
    // ---- A staging: 4 chunks/thread; chunk c = tid + 512*o ----
    // rb_local = c>>8, sub = (c>>6)&3, ln = c&63
    size_t asrcb[4];
    int adstb[4];
    #pragma unroll
    for (int o = 0; o < 4; ++o) {
        const int c = tid + 512 * o;
        const int rbl = c >> 8;
        const int sub = (c >> 6) & 3;
        const int ln = c & 63;
        asrcb[o] = ((size_t)((bt * 8 + rbl) * 8 + nblk) << 16) + (size_t)sub * 1024 + (size_t)ln * 16;
        adstb[o] = c * 16;
    }

    // ---- read offsets ----
    const int boffr = (wn * 3) * 1024 + lane * 16;        // + u*6144 within slot
    const int aoffr0 = (2 * wm) * 4096 + lane * 16;       // rb_local 2wm, + u*1024
    const int aoffr1 = (2 * wm + 1) * 4096 + lane * 16;   // rb_local 2wm+1

    f32x16 acc_r[2] = {};
    f32x16 acc_z[2] = {};
    f32x16 acc_nx[2] = {};
    f32x16 acc_nh[2] = {};

    auto stageA = [&](int it, int slot) {     // 4 ops
        const int ic = it > 15 ? 15 : it;
        char* dst = (char*)&ldsA[slot][0];
        #pragma unroll
        for (int o = 0; o < 4; ++o)
            __builtin_amdgcn_global_load_lds(G1CAST((const char*)Afrag + asrcb[o] + (size_t)ic * 4096),
                                             L3CAST(dst + adstb[o]), 16, 0, 0);
    };
    auto stageB = [&](int it, int slot) {     // 3 ops
        const int ic = it > 15 ? 15 : it;
        const char* src = bsrc0 + (size_t)ic * 24576;
        char* dst = (char*)&ldsB[slot][0] + bdst0;
        #pragma unroll
        for (int o = 0; o < 3; ++o)
            __builtin_amdgcn_global_load_lds(G1CAST(src + o * 1024),
                                             L3CAST(dst + o * 1024), 16, 0, 0);
    };

#define SUBSTEP(u, accN)                                                            \
    {                                                                               \
        const char* bp = (const char*)&ldsB[rslot][0] + (u) * 6144 + boffr;         \
        const char* ap = (const char*)&ldsA[i_ & 1][0] + (u) * 1024;                \
        bf16x8 a0 = *(const bf16x8*)(ap + aoffr0);                                  \
        bf16x8 a1 = *(const bf16x8*)(ap + aoffr1);                                  \
        bf16x8 b0 = *(const bf16x8*)(bp);                                           \
        bf16x8 b1 = *(const bf16x8*)(bp + 1024);                                    \
        bf16x8 b2 = *(const bf16x8*)(bp + 2048);                                    \
        acc_r[0] = __builtin_amdgcn_mfma_f32_32x32x16_bf16(a0, b0, acc_r[0], 0, 0, 0); \
        acc_r[1] = __builtin_amdgcn_mfma_f32_32x32x16_bf16(a1, b0, acc_r[1], 0, 0, 0); \
        acc_z[0] = __builtin_amdgcn_mfma_f32_32x32x16_bf16(a0, b1, acc_z[0], 0, 0, 0); \
        acc_z[1] = __builtin_amdgcn_mfma_f32_32x32x16_bf16(a1, b1, acc_z[1], 0, 0, 0); \
        accN[0]  = __builtin_amdgcn_mfma_f32_32x32x16_bf16(a0, b2, accN[0], 0, 0, 0);  \
        accN[1]  = __builtin_amdgcn_mfma_f32_32x32x16_bf16(a1, b2, accN[1], 0, 0, 0);  \
    }

#define ITER(accN)                                                                  \
    {                                                                               \
        asm volatile("s_waitcnt vmcnt(3)" ::: "memory");                            \
        __builtin_amdgcn_s_barrier();                                               \
        stageA(i_ + 1, (i_ + 1) & 1);                                               \
        stageB(i_ + 2, stslot);                                                     \
        SUBSTEP(0, accN)                                                            \
        SUBSTEP(1, accN)                                                            \
        SUBSTEP(2, accN)                                                            \
        SUBSTEP(3, accN)                                                            \
        rslot = (rslot == 2) ? 0 : rslot + 1;                                       \
        stslot = (stslot == 2) ? 0 : stslot + 1;                                    \
        i_ += 1;                                                                    \
    }

    // prologue, issue order = steady-state FIFO: B(0), A(0), B(1)  (10 ops)
    stageB(0, 0);
    stageA(0, 0);
    stageB(1, 1);

    int i_ = 0;
    int rslot = 0;                            // B slot i%3
    int stslot = 2;                           // B slot (i+2)%3

    #pragma unroll 1
    for (int g2 = 0; g2 < 8; ++g2) {          // iters 0..7: k 0..511 -> acc_nx
        ITER(acc_nx)
    }
    #pragma unroll 1
    for (int g2 = 0; g2 < 8; ++g2) {          // iters 8..15: k 512..1023 -> acc_nh
        ITER(acc_nh)
    }
#undef ITER
#undef SUBSTEP

    // ---- epilogue: gates + output (wave owns 64x32 tile) ----
    const int jb = jt * 64 + wn * 32 + l31;   // [0,512)
    const int bb = nblk * 1536 + jb;
    const float br = b_ih[bb] + b_hh[bb];
    const float bz = b_ih[bb + 512] + b_hh[bb + 512];
    const float bnx = b_ih[bb + 1024];
    const float bnh = b_hh[bb + 1024];
    const int gcol = nblk * 512 + jb;
    #pragma unroll
    for (int m = 0; m < 2; ++m) {
        #pragma unroll
        for (int rr = 0; rr < 16; ++rr) {
            const int rowl = (rr & 3) + 8 * (rr >> 2) + 4 * k8;
            const int row = brow0 + wm * 64 + m * 32 + rowl;
            const size_t idx = (size_t)row * 4096 + gcol;
            const float sr = acc_r[m][rr] + br;
            const float sz = acc_z[m][rr] + bz;
            const float rg = 1.f / (1.f + __expf(-sr));
            const float zg = 1.f / (1.f + __expf(-sz));
            const float tin = (acc_nx[m][rr] + bnx) + rg * (acc_nh[m][rr] + bnh);
            const float e2 = __expf(-2.f * tin);
            const float ng = 2.f / (1.f + e2) - 1.f;
            const float hv = hst[idx];
            out[idx] = ng + zg * (hv - ng);
        }
    }
}

extern "C" void kernel_launch(void* const* d_in, const int* in_sizes, int n_in,
                              void* d_out, int out_size, void* d_ws, size_t ws_size,
                              hipStream_t stream) {
    (void)in_sizes; (void)n_in; (void)out_size; (void)ws_size;
    const float* x    = (const float*)d_in[0];
    const float* h    = (const float*)d_in[1];
    const float* W_ih = (const float*)d_in[2];
    const float* W_hh = (const float*)d_in[3];
    const float* b_ih = (const float*)d_in[4];
    const float* b_hh = (const float*)d_in[5];
    short* Wstep = (short*)d_ws;                              // 24 MB
    short* Afrag = (short*)d_ws + (size_t)12 * 1024 * 1024;   // 16 MB

    wconv_kernel<<<6144, 256, 0, stream>>>(W_ih, W_hh, Wstep);
    aconv_kernel<<<4096, 256, 0, stream>>>(x, h, Afrag);
    gru_kernel<<<256, 512, 0, stream>>>(h, Wstep, Afrag, b_ih, b_hh, (float*)d_out);
}

// Round 20
// 60.581 us; speedup vs baseline: 1.1542x; 1.0346x over previous
//
#include <hip/hip_runtime.h>
#include <hip/hip_bf16.h>
#include <stdint.h>

typedef short bf16x8 __attribute__((ext_vector_type(8)));
typedef float f32x16 __attribute__((ext_vector_type(16)));

static __device__ __forceinline__ short f2bf(float f) {
    __hip_bfloat16 b = __float2bfloat16(f);
    return __builtin_bit_cast(short, b);
}

// ---------------------------------------------------------------------------
// Kernel 1: weights -> bf16 in exact MFMA-fragment order (R11-passed).
// gid = ((((nblk*16 + jt*2 + wn)*3 + g)*16 + ks)*4 + ksub)*64 + lane
//   j  = jt*64 + wn*32 + (lane&31)
//   kk = ks*64 + ksub*16 + (lane>>5)*8 + t, t=0..7
//   kk < 512 -> W_ih[nblk][g*512+j][kk], else W_hh[nblk][g*512+j][kk-512]
// Writer XCD (b%8) == consumer XCD (nblk).
// ---------------------------------------------------------------------------
__global__ __launch_bounds__(256) void wconv_kernel(const float* __restrict__ Wih,
                                                    const float* __restrict__ Whh,
                                                    short* __restrict__ Wfrag) {
    const int b = blockIdx.x;                         // 6144
    const int vb = (b & 7) * 768 + (b >> 3);          // XCD-aligned permute
    const int gid = vb * 256 + threadIdx.x;
    const int lane = gid & 63;
    const int ksub = (gid >> 6) & 3;
    const int ks   = (gid >> 8) & 15;
    int s = gid >> 12;                                // 0..383
    const int g = s % 3; s /= 3;
    const int wn = s & 1;
    const int jt = (s >> 1) & 7;
    const int nblk = s >> 4;
    const int j = jt * 64 + wn * 32 + (lane & 31);
    const int kk = ks * 64 + ksub * 16 + (lane >> 5) * 8;
    const float* src = (kk < 512)
        ? Wih + ((int64_t)nblk * 786432 + (int64_t)(g * 512 + j) * 512 + kk)
        : Whh + ((int64_t)nblk * 786432 + (int64_t)(g * 512 + j) * 512 + (kk - 512));
    const float4 a = ((const float4*)src)[0];
    const float4 bq = ((const float4*)src)[1];
    bf16x8 o;
    o[0] = f2bf(a.x); o[1] = f2bf(a.y); o[2] = f2bf(a.z); o[3] = f2bf(a.w);
    o[4] = f2bf(bq.x); o[5] = f2bf(bq.y); o[6] = f2bf(bq.z); o[7] = f2bf(bq.w);
    *(bf16x8*)(Wfrag + (size_t)gid * 8) = o;
}

// ---------------------------------------------------------------------------
// Kernel 1b: x,h -> bf16 A-image in MFMA fragment order (R11-passed).
// Afrag[rb 0..31][nblk 0..7][s 0..63][lane 0..63][8 bf16]:
//   row = rb*32 + (lane&31),  kk = s*16 + (lane>>5)*8   (kk<512 = x, else h)
// ---------------------------------------------------------------------------
__global__ __launch_bounds__(256) void aconv_kernel(const float* __restrict__ x,
                                                    const float* __restrict__ h,
                                                    short* __restrict__ Afrag) {
    const int b = blockIdx.x;                 // 4096
    const int n = b & 7;                      // == consumer XCD
    const int inner = b >> 3;                 // 0..511
    const int rb = inner >> 4;                // 0..31
    const int u = inner & 15;                 // 0..15
    const int tid = threadIdx.x;
    const int lane = tid & 63;
    const int s = u * 4 + (tid >> 6);         // 0..63
    const int row = rb * 32 + (lane & 31);
    const int kk = s * 16 + (lane >> 5) * 8;  // 0..1023
    const float* src = (kk < 512)
        ? x + ((size_t)row * 4096 + n * 512 + kk)
        : h + ((size_t)row * 4096 + n * 512 + (kk - 512));
    const float4 a = ((const float4*)src)[0];
    const float4 bq = ((const float4*)src)[1];
    bf16x8 o;
    o[0] = f2bf(a.x); o[1] = f2bf(a.y); o[2] = f2bf(a.z); o[3] = f2bf(a.w);
    o[4] = f2bf(bq.x); o[5] = f2bf(bq.y); o[6] = f2bf(bq.z); o[7] = f2bf(bq.w);
    const size_t dst = ((((size_t)(rb * 8 + n) * 64 + s) * 64) + lane) * 8;
    *(bf16x8*)(Afrag + dst) = o;
}

// ---------------------------------------------------------------------------
// Kernel 2: fused block-diagonal GRU — register-only, DISTANCE-3 prefetch,
// zero-VALU pointer-bump addressing, no barriers/LDS.
// BM=256 x BN=64(x3 gates), 512 thr = 8 waves (4wm x 2wn), wave tile 64x32
// (m_rep=2), acc = 8 x f32x16 = 128 regs. Grid 256 = 1 block/CU.
// Period-4 named sets; iter s uses set s%4 and loads step s+3 into set
// (s+3)%4 (== (s-1)%4, consumed at s-1: safe). 15 loads in flight/wave.
// Tail peeled: iters 61..63 load nothing (no clamps anywhere).
// ---------------------------------------------------------------------------
__global__ __launch_bounds__(512, 2) void gru_kernel(
    const float* __restrict__ hst,
    const short* __restrict__ Wfrag, const short* __restrict__ Afrag,
    const float* __restrict__ b_ih, const float* __restrict__ b_hh,
    float* __restrict__ out)
{
    const int tid = threadIdx.x;
    const int nblk = blockIdx.x & 7;          // XCD-local weight slice
    const int rr_ = blockIdx.x >> 3;          // 0..31
    const int bt = rr_ >> 3;                  // 0..3 batch tile (slow)
    const int jt = rr_ & 7;                   // j tile (fast -> L2 reuse)
    const int brow0 = bt * 256;

    const int lane = tid & 63;
    const int wave = tid >> 6;                // 0..7
    const int wm = wave >> 1;                 // 0..3 (64-row slice)
    const int wn = wave & 1;                  // 0..1 (32-col slice)
    const int l31 = lane & 31;
    const int k8 = lane >> 5;

    // A fragment bases: rb0 = 32-row tile of rows [brow0+wm*64, +32)
    const int rb0 = (brow0 + wm * 64) >> 5;
    const char* pab0 = (const char*)Afrag + ((size_t)(rb0 * 8 + nblk) << 16) + (size_t)lane * 16;
    const char* pab1 = pab0 + (8 << 16);      // rb0 + 1
    const char* pwb = (const char*)Wfrag
        + ((size_t)((nblk * 16 + jt * 2 + wn) * 3) << 16) + (size_t)lane * 16;

    f32x16 acc_r[2] = {};
    f32x16 acc_z[2] = {};
    f32x16 acc_nx[2] = {};
    f32x16 acc_nh[2] = {};

    bf16x8 a0P, a1P, b0P, b1P, b2P;
    bf16x8 a0Q, a1Q, b0Q, b1Q, b2Q;
    bf16x8 a0R, a1R, b0R, b1R, b2R;
    bf16x8 a0S, a1S, b0S, b1S, b2S;

// load the NEXT step (pointer-bump; no clamp, no index math)
#define LDSET(T)                                                           \
    {                                                                      \
        a0##T = *(const bf16x8*)pab0;                                      \
        a1##T = *(const bf16x8*)pab1;                                      \
        b0##T = *(const bf16x8*)pwb;                                       \
        b1##T = *(const bf16x8*)(pwb + 65536);                             \
        b2##T = *(const bf16x8*)(pwb + 131072);                            \
        pab0 += 1024; pab1 += 1024; pwb += 1024;                           \
    }

#define FMSET(T, accN)                                                             \
    {                                                                              \
        acc_r[0] = __builtin_amdgcn_mfma_f32_32x32x16_bf16(a0##T, b0##T, acc_r[0], 0, 0, 0); \
        acc_r[1] = __builtin_amdgcn_mfma_f32_32x32x16_bf16(a1##T, b0##T, acc_r[1], 0, 0, 0); \
        acc_z[0] = __builtin_amdgcn_mfma_f32_32x32x16_bf16(a0##T, b1##T, acc_z[0], 0, 0, 0); \
        acc_z[1] = __builtin_amdgcn_mfma_f32_32x32x16_bf16(a1##T, b1##T, acc_z[1], 0, 0, 0); \
        accN[0]  = __builtin_amdgcn_mfma_f32_32x32x16_bf16(a0##T, b2##T, accN[0], 0, 0, 0);  \
        accN[1]  = __builtin_amdgcn_mfma_f32_32x32x16_bf16(a1##T, b2##T, accN[1], 0, 0, 0);  \
    }

    // prologue: steps 0,1,2 -> sets P,Q,R (15 loads in flight)
    LDSET(P) LDSET(Q) LDSET(R)

    // iters 0..31 -> acc_nx (8 groups of 4)
    #pragma unroll 1
    for (int grp = 0; grp < 8; ++grp) {
        LDSET(S) FMSET(P, acc_nx)             // iter 4g+0: load step s+3
        LDSET(P) FMSET(Q, acc_nx)
        LDSET(Q) FMSET(R, acc_nx)
        LDSET(R) FMSET(S, acc_nx)
    }
    // iters 32..59 -> acc_nh (7 groups of 4)
    #pragma unroll 1
    for (int grp = 0; grp < 7; ++grp) {
        LDSET(S) FMSET(P, acc_nh)
        LDSET(P) FMSET(Q, acc_nh)
        LDSET(Q) FMSET(R, acc_nh)
        LDSET(R) FMSET(S, acc_nh)
    }
    // iter 60: load step 63 (the last), then drain
    LDSET(S) FMSET(P, acc_nh)
    FMSET(Q, acc_nh)                          // iter 61
    FMSET(R, acc_nh)                          // iter 62
    FMSET(S, acc_nh)                          // iter 63
#undef LDSET
#undef FMSET

    // ---- epilogue: gates + output (wave owns 64x32 tile) ----
    const int jb = jt * 64 + wn * 32 + l31;   // [0,512)
    const int bb = nblk * 1536 + jb;
    const float br = b_ih[bb] + b_hh[bb];
    const float bz = b_ih[bb + 512] + b_hh[bb + 512];
    const float bnx = b_ih[bb + 1024];
    const float bnh = b_hh[bb + 1024];
    const int gcol = nblk * 512 + jb;
    #pragma unroll
    for (int m = 0; m < 2; ++m) {
        #pragma unroll
        for (int rr = 0; rr < 16; ++rr) {
            const int rowl = (rr & 3) + 8 * (rr >> 2) + 4 * k8;
            const int row = brow0 + wm * 64 + m * 32 + rowl;
            const size_t idx = (size_t)row * 4096 + gcol;
            const float sr = acc_r[m][rr] + br;
            const float sz = acc_z[m][rr] + bz;
            const float rg = 1.f / (1.f + __expf(-sr));
            const float zg = 1.f / (1.f + __expf(-sz));
            const float tin = (acc_nx[m][rr] + bnx) + rg * (acc_nh[m][rr] + bnh);
            const float e2 = __expf(-2.f * tin);
            const float ng = 2.f / (1.f + e2) - 1.f;
            const float hv = hst[idx];
            out[idx] = ng + zg * (hv - ng);
        }
    }
}

extern "C" void kernel_launch(void* const* d_in, const int* in_sizes, int n_in,
                              void* d_out, int out_size, void* d_ws, size_t ws_size,
                              hipStream_t stream) {
    (void)in_sizes; (void)n_in; (void)out_size; (void)ws_size;
    const float* x    = (const float*)d_in[0];
    const float* h    = (const float*)d_in[1];
    const float* W_ih = (const float*)d_in[2];
    const float* W_hh = (const float*)d_in[3];
    const float* b_ih = (const float*)d_in[4];
    const float* b_hh = (const float*)d_in[5];
    short* Wfrag = (short*)d_ws;                              // 24 MB
    short* Afrag = (short*)d_ws + (size_t)12 * 1024 * 1024;   // 16 MB

    wconv_kernel<<<6144, 256, 0, stream>>>(W_ih, W_hh, Wfrag);
    aconv_kernel<<<4096, 256, 0, stream>>>(x, h, Afrag);
    gru_kernel<<<256, 512, 0, stream>>>(h, Wfrag, Afrag, b_ih, b_hh, (float*)d_out);
}